// Round 2
// baseline (1486.064 us; speedup 1.0000x reference)
//
#include <hip/hip_runtime.h>

#define CC 64      // channels
#define SS 16384   // D*W*H = 16*32*32
#define NN 65536   // B*SS
#define KK 2048    // codebook size

// -------------------- kernel 1: pre = W_in @ x + b_in (fp64 accum) -------
// thread = token, channel-major layout. Accumulate in fp64 so stored fp32
// xf is correctly-rounded -> argmin matches the high-precision reference.
__global__ __launch_bounds__(256) void vq_conv_in(
    const float* __restrict__ x, const float* __restrict__ w_in,
    const float* __restrict__ b_in, float* __restrict__ xf) {
  __shared__ double wt[CC * CC];  // wt[ci*64+o] = (double)w_in[o*64+ci]
  int t = threadIdx.x;
  for (int i = t; i < CC * CC; i += 256) {
    wt[i] = (double)w_in[((i & 63) << 6) | (i >> 6)];
  }
  __syncthreads();
  int n = blockIdx.x * 256 + t;
  int b = n >> 14, s = n & (SS - 1);
  const float* xb = x + (size_t)b * CC * SS + s;
  double acc[CC];
#pragma unroll
  for (int o = 0; o < CC; ++o) acc[o] = (double)b_in[o];
#pragma unroll 2
  for (int ci = 0; ci < CC; ++ci) {
    double xv = (double)xb[(size_t)ci * SS];
    const double* wr = &wt[ci * CC];
#pragma unroll 8
    for (int o = 0; o < CC; ++o) acc[o] = fma(wr[o], xv, acc[o]);
  }
  float* ob = xf + (size_t)b * CC * SS + s;
#pragma unroll
  for (int o = 0; o < CC; ++o) ob[(size_t)o * SS] = (float)acc[o];
}

// -------------------- kernel 2: code norms --------------------
__global__ __launch_bounds__(256) void vq_cnorm(
    const float* __restrict__ cb, float* __restrict__ cnorm) {
  int k = blockIdx.x * 256 + threadIdx.x;
  const float4* r = (const float4*)(cb + (size_t)k * CC);
  float s = 0.f;
#pragma unroll
  for (int i = 0; i < 16; ++i) {
    float4 v = r[i];
    s = fmaf(v.x, v.x, s);
    s = fmaf(v.y, v.y, s);
    s = fmaf(v.z, v.z, s);
    s = fmaf(v.w, v.w, s);
  }
  cnorm[k] = s;
}

// -------------------- kernel 3: approx top-2 per K-half -------------------
// blockIdx.x bit0 = k-half (wave-uniform), rest = token group of 128.
// fp32 expanded-form distances; keeps best AND second-best index. Exact
// fp64 re-rank happens in the gather kernel over the 4 candidates.
__global__ __launch_bounds__(128) void vq_argmin(
    const float* __restrict__ xf, const float* __restrict__ cb,
    const float* __restrict__ cnorm, int* __restrict__ cidx) {
  int half = blockIdx.x & 1;
  int n = (blockIdx.x >> 1) * 128 + threadIdx.x;
  int b = n >> 14, s = n & (SS - 1);
  const float* xb = xf + (size_t)b * CC * SS + s;
  float xv[CC];
#pragma unroll
  for (int c = 0; c < CC; ++c) xv[c] = xb[(size_t)c * SS];

  float best = 3.402823466e+38f, second = 3.402823466e+38f;
  int bi = 0, si = 0;
  const int k0 = half * (KK / 2);
  const float4* cb4 = (const float4*)cb;
  for (int k = k0; k < k0 + KK / 2; k += 4) {
    float d0 = 0.f, d1 = 0.f, d2 = 0.f, d3 = 0.f;
#pragma unroll
    for (int c4 = 0; c4 < 16; ++c4) {
      float4 w0 = cb4[(size_t)(k + 0) * 16 + c4];
      float4 w1 = cb4[(size_t)(k + 1) * 16 + c4];
      float4 w2 = cb4[(size_t)(k + 2) * 16 + c4];
      float4 w3 = cb4[(size_t)(k + 3) * 16 + c4];
      d0 = fmaf(xv[c4 * 4 + 0], w0.x, d0);
      d0 = fmaf(xv[c4 * 4 + 1], w0.y, d0);
      d0 = fmaf(xv[c4 * 4 + 2], w0.z, d0);
      d0 = fmaf(xv[c4 * 4 + 3], w0.w, d0);
      d1 = fmaf(xv[c4 * 4 + 0], w1.x, d1);
      d1 = fmaf(xv[c4 * 4 + 1], w1.y, d1);
      d1 = fmaf(xv[c4 * 4 + 2], w1.z, d1);
      d1 = fmaf(xv[c4 * 4 + 3], w1.w, d1);
      d2 = fmaf(xv[c4 * 4 + 0], w2.x, d2);
      d2 = fmaf(xv[c4 * 4 + 1], w2.y, d2);
      d2 = fmaf(xv[c4 * 4 + 2], w2.z, d2);
      d2 = fmaf(xv[c4 * 4 + 3], w2.w, d2);
      d3 = fmaf(xv[c4 * 4 + 0], w3.x, d3);
      d3 = fmaf(xv[c4 * 4 + 1], w3.y, d3);
      d3 = fmaf(xv[c4 * 4 + 2], w3.z, d3);
      d3 = fmaf(xv[c4 * 4 + 3], w3.w, d3);
    }
    float D0 = fmaf(-2.f, d0, cnorm[k + 0]);
    float D1 = fmaf(-2.f, d1, cnorm[k + 1]);
    float D2 = fmaf(-2.f, d2, cnorm[k + 2]);
    float D3 = fmaf(-2.f, d3, cnorm[k + 3]);
    if (D0 < best) { second = best; si = bi; best = D0; bi = k + 0; }
    else if (D0 < second) { second = D0; si = k + 0; }
    if (D1 < best) { second = best; si = bi; best = D1; bi = k + 1; }
    else if (D1 < second) { second = D1; si = k + 1; }
    if (D2 < best) { second = best; si = bi; best = D2; bi = k + 2; }
    else if (D2 < second) { second = D2; si = k + 2; }
    if (D3 < best) { second = best; si = bi; best = D3; bi = k + 3; }
    else if (D3 < second) { second = D3; si = k + 3; }
  }
  cidx[(size_t)(2 * half + 0) * NN + n] = bi;
  cidx[(size_t)(2 * half + 1) * NN + n] = si;
}

// ------------- kernel 4: fp64 re-rank, gather q, losses, conv_out ---------
__global__ __launch_bounds__(256) void vq_gather_out(
    const float* __restrict__ cb, const float* __restrict__ w_out,
    const float* __restrict__ b_out, const int* __restrict__ cidx,
    float* __restrict__ dout, float* __restrict__ loss_acc) {
  __shared__ float wt[CC * CC];  // wt[c*64+o] = w_out[o*64+c]
  int t = threadIdx.x;
  for (int i = t; i < CC * CC; i += 256) {
    wt[i] = w_out[((i & 63) << 6) | (i >> 6)];
  }
  __syncthreads();
  int n = blockIdx.x * 256 + t;
  int b = n >> 14, s = n & (SS - 1);

  // load this token's xf (fp32, correctly rounded from fp64)
  float* zb = dout + (size_t)NN * CC + (size_t)b * CC * SS + s;
  float xfv[CC];
#pragma unroll
  for (int c = 0; c < CC; ++c) xfv[c] = zb[(size_t)c * SS];

  // exact fp64 re-rank of the 4 candidates (direct form: no cancellation)
  int cand0 = cidx[n];
  int cand1 = cidx[(size_t)NN + n];
  int cand2 = cidx[(size_t)2 * NN + n];
  int cand3 = cidx[(size_t)3 * NN + n];
  double bestd = 1.0e300;
  int id = 0x7fffffff;
#pragma unroll
  for (int j = 0; j < 4; ++j) {
    int kj = (j == 0) ? cand0 : (j == 1) ? cand1 : (j == 2) ? cand2 : cand3;
    const float* cr = cb + (size_t)kj * CC;
    double dj = 0.0;
#pragma unroll 8
    for (int c = 0; c < CC; ++c) {
      double df = (double)xfv[c] - (double)cr[c];
      dj = fma(df, df, dj);
    }
    if (dj < bestd || (dj == bestd && kj < id)) { bestd = dj; id = kj; }
  }

  // gather q
  float q[CC];
  const float4* qr = (const float4*)(cb + (size_t)id * CC);
#pragma unroll
  for (int i = 0; i < 16; ++i) {
    float4 v = qr[i];
    q[i * 4 + 0] = v.x;
    q[i * 4 + 1] = v.y;
    q[i * 4 + 2] = v.z;
    q[i * 4 + 3] = v.w;
  }

  // loss partial + write z = q
  float lsum = 0.f;
#pragma unroll
  for (int c = 0; c < CC; ++c) {
    float df = q[c] - xfv[c];
    lsum = fmaf(df, df, lsum);
    zb[(size_t)c * SS] = q[c];
  }

  // out = W_out @ q + b_out
  float acc[CC];
#pragma unroll
  for (int o = 0; o < CC; ++o) acc[o] = b_out[o];
#pragma unroll 4
  for (int c = 0; c < CC; ++c) {
    float qv = q[c];
    const float4* w4 = (const float4*)&wt[c * CC];
#pragma unroll
    for (int o4 = 0; o4 < 16; ++o4) {
      float4 w = w4[o4];
      acc[o4 * 4 + 0] = fmaf(w.x, qv, acc[o4 * 4 + 0]);
      acc[o4 * 4 + 1] = fmaf(w.y, qv, acc[o4 * 4 + 1]);
      acc[o4 * 4 + 2] = fmaf(w.z, qv, acc[o4 * 4 + 2]);
      acc[o4 * 4 + 3] = fmaf(w.w, qv, acc[o4 * 4 + 3]);
    }
  }
  float* ob = dout + (size_t)b * CC * SS + s;
#pragma unroll
  for (int o = 0; o < CC; ++o) ob[(size_t)o * SS] = acc[o];

  // block-reduce loss, one atomic per block
#pragma unroll
  for (int off = 32; off > 0; off >>= 1) lsum += __shfl_down(lsum, off, 64);
  __shared__ float wsum[4];
  if ((t & 63) == 0) wsum[t >> 6] = lsum;
  __syncthreads();
  if (t == 0) {
    atomicAdd(loss_acc, wsum[0] + wsum[1] + wsum[2] + wsum[3]);
  }
}

// -------------------- kernel 5: finalize scalar losses --------------------
__global__ void vq_finalize(const float* __restrict__ loss_acc,
                            float* __restrict__ dout) {
  float l = loss_acc[0] * (1.0f / (float)((size_t)NN * CC));
  dout[(size_t)2 * NN * CC + 0] = l;  // codebook_loss
  dout[(size_t)2 * NN * CC + 1] = l;  // commitment_loss (same forward value)
}

extern "C" void kernel_launch(void* const* d_in, const int* in_sizes, int n_in,
                              void* d_out, int out_size, void* d_ws,
                              size_t ws_size, hipStream_t stream) {
  const float* x = (const float*)d_in[0];
  const float* cb = (const float*)d_in[1];
  const float* w_in = (const float*)d_in[2];
  const float* b_in = (const float*)d_in[3];
  const float* w_out = (const float*)d_in[4];
  const float* b_out = (const float*)d_in[5];
  float* out = (float*)d_out;
  float* zreg = out + (size_t)NN * CC;  // z region doubles as xf scratch

  // workspace layout (bytes): [0,4) loss acc; [1024,9216) cnorm;
  // [16384, 16384+1M) candidate idx (4 per token). ~1.06 MB total.
  float* loss_acc = (float*)d_ws;
  float* cnorm = (float*)((char*)d_ws + 1024);
  int* cidx = (int*)((char*)d_ws + 16384);

  hipMemsetAsync(d_ws, 0, 4, stream);  // zero loss accumulator (capturable)

  vq_conv_in<<<NN / 256, 256, 0, stream>>>(x, w_in, b_in, zreg);
  vq_cnorm<<<KK / 256, 256, 0, stream>>>(cb, cnorm);
  vq_argmin<<<(NN / 128) * 2, 128, 0, stream>>>(zreg, cb, cnorm, cidx);
  vq_gather_out<<<NN / 256, 256, 0, stream>>>(cb, w_out, b_out, cidx, out,
                                              loss_acc);
  vq_finalize<<<1, 1, 0, stream>>>(loss_acc, out);
}

// Round 3
// 1180.936 us; speedup vs baseline: 1.2584x; 1.2584x over previous
//
#include <hip/hip_runtime.h>

#define CC 64      // channels
#define SS 16384   // D*W*H = 16*32*32
#define NN 65536   // B*SS
#define KK 2048    // codebook size

// -------------------- kernel 1: pre = W_in @ x + b_in (fp64 accum) -------
// thread = token, channel-major layout. Accumulate in fp64 so stored fp32
// xf is correctly-rounded -> argmin matches the high-precision reference.
// launch_bounds(256,2): acc[64] fp64 = 128 VGPRs must stay resident.
__global__ __launch_bounds__(256, 2) void vq_conv_in(
    const float* __restrict__ x, const float* __restrict__ w_in,
    const float* __restrict__ b_in, float* __restrict__ xf) {
  __shared__ double wt[CC * CC];  // wt[ci*64+o] = (double)w_in[o*64+ci]
  int t = threadIdx.x;
  for (int i = t; i < CC * CC; i += 256) {
    wt[i] = (double)w_in[((i & 63) << 6) | (i >> 6)];
  }
  __syncthreads();
  int n = blockIdx.x * 256 + t;
  int b = n >> 14, s = n & (SS - 1);
  const float* xb = x + (size_t)b * CC * SS + s;
  double acc[CC];
#pragma unroll
  for (int o = 0; o < CC; ++o) acc[o] = (double)b_in[o];
#pragma unroll 2
  for (int ci = 0; ci < CC; ++ci) {
    double xv = (double)xb[(size_t)ci * SS];
    const double* wr = &wt[ci * CC];
#pragma unroll 8
    for (int o = 0; o < CC; ++o) acc[o] = fma(wr[o], xv, acc[o]);
  }
  float* ob = xf + (size_t)b * CC * SS + s;
#pragma unroll
  for (int o = 0; o < CC; ++o) ob[(size_t)o * SS] = (float)acc[o];
}

// -------------------- kernel 2: code norms --------------------
__global__ __launch_bounds__(256) void vq_cnorm(
    const float* __restrict__ cb, float* __restrict__ cnorm) {
  int k = blockIdx.x * 256 + threadIdx.x;
  const float4* r = (const float4*)(cb + (size_t)k * CC);
  float s = 0.f;
#pragma unroll
  for (int i = 0; i < 16; ++i) {
    float4 v = r[i];
    s = fmaf(v.x, v.x, s);
    s = fmaf(v.y, v.y, s);
    s = fmaf(v.z, v.z, s);
    s = fmaf(v.w, v.w, s);
  }
  cnorm[k] = s;
}

// -------------------- kernel 3: approx top-2 per K-quarter ----------------
// blockIdx.x bits[1:0] = k-quarter (wave-uniform), rest = token group of 128.
// fp32 expanded-form distances; keeps best AND second-best index per quarter.
// Exact fp64 re-rank over the 8 candidates happens in the gather kernel.
// launch_bounds(128,2): VGPR cap 256 so xv[64] stays in registers (R2 spilled
// at VGPR_Count=44 -> 953us; this is the fix).
__global__ __launch_bounds__(128, 2) void vq_argmin(
    const float* __restrict__ xf, const float* __restrict__ cb,
    const float* __restrict__ cnorm, int* __restrict__ cidx) {
  int quarter = blockIdx.x & 3;
  int n = (blockIdx.x >> 2) * 128 + threadIdx.x;
  int b = n >> 14, s = n & (SS - 1);
  const float* xb = xf + (size_t)b * CC * SS + s;
  float xv[CC];
#pragma unroll
  for (int c = 0; c < CC; ++c) xv[c] = xb[(size_t)c * SS];

  float best = 3.402823466e+38f, second = 3.402823466e+38f;
  int bi = 0, si = 0;
  const int k0 = quarter * (KK / 4);
  const float4* cbp = (const float4*)cb + (size_t)k0 * 16;
  for (int kk = 0; kk < KK / 4; kk += 4, cbp += 64) {
    float d0 = 0.f, d1 = 0.f, d2 = 0.f, d3 = 0.f;
#pragma unroll
    for (int c4 = 0; c4 < 16; ++c4) {
      float4 w0 = cbp[c4];
      float4 w1 = cbp[16 + c4];
      float4 w2 = cbp[32 + c4];
      float4 w3 = cbp[48 + c4];
      d0 = fmaf(xv[c4 * 4 + 0], w0.x, d0);
      d0 = fmaf(xv[c4 * 4 + 1], w0.y, d0);
      d0 = fmaf(xv[c4 * 4 + 2], w0.z, d0);
      d0 = fmaf(xv[c4 * 4 + 3], w0.w, d0);
      d1 = fmaf(xv[c4 * 4 + 0], w1.x, d1);
      d1 = fmaf(xv[c4 * 4 + 1], w1.y, d1);
      d1 = fmaf(xv[c4 * 4 + 2], w1.z, d1);
      d1 = fmaf(xv[c4 * 4 + 3], w1.w, d1);
      d2 = fmaf(xv[c4 * 4 + 0], w2.x, d2);
      d2 = fmaf(xv[c4 * 4 + 1], w2.y, d2);
      d2 = fmaf(xv[c4 * 4 + 2], w2.z, d2);
      d2 = fmaf(xv[c4 * 4 + 3], w2.w, d2);
      d3 = fmaf(xv[c4 * 4 + 0], w3.x, d3);
      d3 = fmaf(xv[c4 * 4 + 1], w3.y, d3);
      d3 = fmaf(xv[c4 * 4 + 2], w3.z, d3);
      d3 = fmaf(xv[c4 * 4 + 3], w3.w, d3);
    }
    int k = k0 + kk;
    float D0 = fmaf(-2.f, d0, cnorm[k + 0]);
    float D1 = fmaf(-2.f, d1, cnorm[k + 1]);
    float D2 = fmaf(-2.f, d2, cnorm[k + 2]);
    float D3 = fmaf(-2.f, d3, cnorm[k + 3]);
    if (D0 < best) { second = best; si = bi; best = D0; bi = k + 0; }
    else if (D0 < second) { second = D0; si = k + 0; }
    if (D1 < best) { second = best; si = bi; best = D1; bi = k + 1; }
    else if (D1 < second) { second = D1; si = k + 1; }
    if (D2 < best) { second = best; si = bi; best = D2; bi = k + 2; }
    else if (D2 < second) { second = D2; si = k + 2; }
    if (D3 < best) { second = best; si = bi; best = D3; bi = k + 3; }
    else if (D3 < second) { second = D3; si = k + 3; }
  }
  cidx[(size_t)(2 * quarter + 0) * NN + n] = bi;
  cidx[(size_t)(2 * quarter + 1) * NN + n] = si;
}

// ------------- kernel 4: fp64 re-rank, gather q, losses, conv_out ---------
__global__ __launch_bounds__(128, 2) void vq_gather_out(
    const float* __restrict__ cb, const float* __restrict__ w_out,
    const float* __restrict__ b_out, const int* __restrict__ cidx,
    float* __restrict__ dout, float* __restrict__ loss_acc) {
  __shared__ float wt[CC * CC];  // wt[c*64+o] = w_out[o*64+c]
  int t = threadIdx.x;
  for (int i = t; i < CC * CC; i += 128) {
    wt[i] = w_out[((i & 63) << 6) | (i >> 6)];
  }
  __syncthreads();
  int n = blockIdx.x * 128 + t;
  int b = n >> 14, s = n & (SS - 1);

  // load this token's xf (fp32, correctly rounded from fp64)
  float* zb = dout + (size_t)NN * CC + (size_t)b * CC * SS + s;
  float xfv[CC];
#pragma unroll
  for (int c = 0; c < CC; ++c) xfv[c] = zb[(size_t)c * SS];

  // exact fp64 re-rank of the 8 candidates (direct form: no cancellation);
  // smallest index wins ties == jnp.argmin first-occurrence.
  double bestd = 1.0e300;
  int id = 0x7fffffff;
#pragma unroll 1
  for (int j = 0; j < 8; ++j) {
    int kj = cidx[(size_t)j * NN + n];
    const float* cr = cb + (size_t)kj * CC;
    double dj = 0.0;
#pragma unroll 8
    for (int c = 0; c < CC; ++c) {
      double df = (double)xfv[c] - (double)cr[c];
      dj = fma(df, df, dj);
    }
    if (dj < bestd || (dj == bestd && kj < id)) { bestd = dj; id = kj; }
  }

  // gather q
  float q[CC];
  const float4* qr = (const float4*)(cb + (size_t)id * CC);
#pragma unroll
  for (int i = 0; i < 16; ++i) {
    float4 v = qr[i];
    q[i * 4 + 0] = v.x;
    q[i * 4 + 1] = v.y;
    q[i * 4 + 2] = v.z;
    q[i * 4 + 3] = v.w;
  }

  // loss partial + write z = q
  float lsum = 0.f;
#pragma unroll
  for (int c = 0; c < CC; ++c) {
    float df = q[c] - xfv[c];
    lsum = fmaf(df, df, lsum);
    zb[(size_t)c * SS] = q[c];
  }

  // out = W_out @ q + b_out
  float acc[CC];
#pragma unroll
  for (int o = 0; o < CC; ++o) acc[o] = b_out[o];
#pragma unroll 4
  for (int c = 0; c < CC; ++c) {
    float qv = q[c];
    const float4* w4 = (const float4*)&wt[c * CC];
#pragma unroll
    for (int o4 = 0; o4 < 16; ++o4) {
      float4 w = w4[o4];
      acc[o4 * 4 + 0] = fmaf(w.x, qv, acc[o4 * 4 + 0]);
      acc[o4 * 4 + 1] = fmaf(w.y, qv, acc[o4 * 4 + 1]);
      acc[o4 * 4 + 2] = fmaf(w.z, qv, acc[o4 * 4 + 2]);
      acc[o4 * 4 + 3] = fmaf(w.w, qv, acc[o4 * 4 + 3]);
    }
  }
  float* ob = dout + (size_t)b * CC * SS + s;
#pragma unroll
  for (int o = 0; o < CC; ++o) ob[(size_t)o * SS] = acc[o];

  // block-reduce loss, one atomic per block
#pragma unroll
  for (int off = 32; off > 0; off >>= 1) lsum += __shfl_down(lsum, off, 64);
  __shared__ float wsum[2];
  if ((t & 63) == 0) wsum[t >> 6] = lsum;
  __syncthreads();
  if (t == 0) {
    atomicAdd(loss_acc, wsum[0] + wsum[1]);
  }
}

// -------------------- kernel 5: finalize scalar losses --------------------
__global__ void vq_finalize(const float* __restrict__ loss_acc,
                            float* __restrict__ dout) {
  float l = loss_acc[0] * (1.0f / (float)((size_t)NN * CC));
  dout[(size_t)2 * NN * CC + 0] = l;  // codebook_loss
  dout[(size_t)2 * NN * CC + 1] = l;  // commitment_loss (same forward value)
}

extern "C" void kernel_launch(void* const* d_in, const int* in_sizes, int n_in,
                              void* d_out, int out_size, void* d_ws,
                              size_t ws_size, hipStream_t stream) {
  const float* x = (const float*)d_in[0];
  const float* cb = (const float*)d_in[1];
  const float* w_in = (const float*)d_in[2];
  const float* b_in = (const float*)d_in[3];
  const float* w_out = (const float*)d_in[4];
  const float* b_out = (const float*)d_in[5];
  float* out = (float*)d_out;
  float* zreg = out + (size_t)NN * CC;  // z region doubles as xf scratch

  // workspace layout (bytes): [0,4) loss acc; [1024,9216) cnorm;
  // [16384, 16384+2M) candidate idx (8 per token). ~2.1 MB total.
  float* loss_acc = (float*)d_ws;
  float* cnorm = (float*)((char*)d_ws + 1024);
  int* cidx = (int*)((char*)d_ws + 16384);

  hipMemsetAsync(d_ws, 0, 4, stream);  // zero loss accumulator (capturable)

  vq_conv_in<<<NN / 256, 256, 0, stream>>>(x, w_in, b_in, zreg);
  vq_cnorm<<<KK / 256, 256, 0, stream>>>(cb, cnorm);
  vq_argmin<<<(NN / 128) * 4, 128, 0, stream>>>(zreg, cb, cnorm, cidx);
  vq_gather_out<<<NN / 128, 128, 0, stream>>>(cb, w_out, b_out, cidx, out,
                                              loss_acc);
  vq_finalize<<<1, 1, 0, stream>>>(loss_acc, out);
}

// Round 4
// 355.438 us; speedup vs baseline: 4.1809x; 3.3225x over previous
//
#include <hip/hip_runtime.h>

#define CC 64      // channels
#define SS 16384   // D*W*H
#define NN 65536   // B*S tokens
#define KK 2048    // codebook size
#define BM 64      // tokens per block tile
#define BK 128     // codes per k-tile (argmin)

// ============ kernel 1: pre = W_in @ x + b_in (fp64 accum, 4x4 tile) =====
// 256 threads = 16 token-groups x 16 outch-groups; acc = 4 tok x 4 oc fp64
// (32 VGPRs) -> no spill. xf stored fp32 correctly-rounded (argmin stability).
__global__ __launch_bounds__(256, 4) void vq_conv_in(
    const float* __restrict__ x, const float* __restrict__ w_in,
    const float* __restrict__ b_in, float* __restrict__ xf) {
  __shared__ float xs[CC][BM];  // xs[ci][tok]
  __shared__ float wt[CC][CC];  // wt[ci][o] = w_in[o][ci]
  int t = threadIdx.x;
  int n0 = blockIdx.x * BM;
  int b = n0 >> 14, s0 = n0 & (SS - 1);
  {  // stage wt transposed: thread -> one o-row, 16 ci
    int o = t >> 2, c0 = (t & 3) * 16;
    const float4* wr = (const float4*)(w_in + o * CC + c0);
#pragma unroll
    for (int i = 0; i < 4; ++i) {
      float4 v = wr[i];
      int ci = c0 + 4 * i;
      wt[ci + 0][o] = v.x; wt[ci + 1][o] = v.y;
      wt[ci + 2][o] = v.z; wt[ci + 3][o] = v.w;
    }
  }
#pragma unroll
  for (int i = 0; i < 4; ++i) {  // stage xs (coalesced rows)
    int e4 = t + 256 * i;
    int ci = e4 >> 4, tok4 = (e4 & 15) * 4;
    *(float4*)&xs[ci][tok4] =
        *(const float4*)(x + (size_t)b * CC * SS + (size_t)ci * SS + s0 + tok4);
  }
  __syncthreads();
  int tx = t & 15, ty = t >> 4;
  double acc[4][4];
#pragma unroll
  for (int j = 0; j < 4; ++j) {
    double bj = (double)b_in[tx * 4 + j];
#pragma unroll
    for (int m = 0; m < 4; ++m) acc[m][j] = bj;
  }
#pragma unroll 8
  for (int ci = 0; ci < CC; ++ci) {
    float4 xq = *(const float4*)&xs[ci][ty * 4];
    float4 wq = *(const float4*)&wt[ci][tx * 4];
    double xm[4] = {xq.x, xq.y, xq.z, xq.w};
    double wm[4] = {wq.x, wq.y, wq.z, wq.w};
#pragma unroll
    for (int m = 0; m < 4; ++m)
#pragma unroll
      for (int j = 0; j < 4; ++j) acc[m][j] = fma(xm[m], wm[j], acc[m][j]);
  }
#pragma unroll
  for (int j = 0; j < 4; ++j) {
    float4 ov = make_float4((float)acc[0][j], (float)acc[1][j],
                            (float)acc[2][j], (float)acc[3][j]);
    *(float4*)(xf + (size_t)b * CC * SS + (size_t)(tx * 4 + j) * SS + s0 +
               ty * 4) = ov;
  }
}

// ============ kernel 2: code norms ============
__global__ __launch_bounds__(256) void vq_cnorm(
    const float* __restrict__ cb, float* __restrict__ cnorm) {
  int k = blockIdx.x * 256 + threadIdx.x;
  const float4* r = (const float4*)(cb + (size_t)k * CC);
  float s = 0.f;
#pragma unroll
  for (int i = 0; i < 16; ++i) {
    float4 v = r[i];
    s = fmaf(v.x, v.x, s); s = fmaf(v.y, v.y, s);
    s = fmaf(v.z, v.z, s); s = fmaf(v.w, v.w, s);
  }
  cnorm[k] = s;
}

// ============ kernel 3: tiled argmin scan, top-2 per tx-octet ============
// Block: 64 tokens x all 2048 codes (16 tiles of 128). Thread (ty,tx):
// 4 tokens x 8 codes, 32 fp32 accs. D = cnorm - 2*dot (xnorm constant per
// token -> argmin-invariant). Ascending-k scan + strict < == first-occurrence
// ties. Octet shuffle-merge (lexicographic) -> 4 candidates/token.
__global__ __launch_bounds__(256, 3) void vq_argmin(
    const float* __restrict__ xf, const float* __restrict__ cb,
    const float* __restrict__ cnorm, int* __restrict__ cidx) {
  __shared__ float xs[CC][BM];  // 16KB
  __shared__ float ct[CC][BK];  // 32KB, ct[ch][code]
  __shared__ float cnt[BK];
  int t = threadIdx.x;
  int n0 = blockIdx.x * BM;
  int b = n0 >> 14, s0 = n0 & (SS - 1);
#pragma unroll
  for (int i = 0; i < 4; ++i) {
    int e4 = t + 256 * i;
    int ci = e4 >> 4, tok4 = (e4 & 15) * 4;
    *(float4*)&xs[ci][tok4] = *(const float4*)(xf + (size_t)b * CC * SS +
                                               (size_t)ci * SS + s0 + tok4);
  }
  int tx = t & 15, ty = t >> 4;
  float best[4], secd[4];
  int bi[4], si[4];
#pragma unroll
  for (int m = 0; m < 4; ++m) {
    best[m] = 3.402823466e+38f; secd[m] = 3.402823466e+38f;
    bi[m] = 0; si[m] = 0;
  }
  for (int kt = 0; kt < KK; kt += BK) {
    {  // stage ct transposed: lane pair shares a code (2-way writes = free)
      int code = t >> 1, c0 = (t & 1) * 32;
      const float4* cr = (const float4*)(cb + (size_t)(kt + code) * CC + c0);
#pragma unroll
      for (int i = 0; i < 8; ++i) {
        float4 v = cr[i];
        int ch = c0 + 4 * i;
        ct[ch + 0][code] = v.x; ct[ch + 1][code] = v.y;
        ct[ch + 2][code] = v.z; ct[ch + 3][code] = v.w;
      }
      if (t < BK / 4) *(float4*)&cnt[t * 4] = *(const float4*)(cnorm + kt + t * 4);
    }
    __syncthreads();
    float acc[4][8];
#pragma unroll
    for (int m = 0; m < 4; ++m)
#pragma unroll
      for (int j = 0; j < 8; ++j) acc[m][j] = 0.f;
#pragma unroll 4
    for (int c = 0; c < CC; ++c) {
      float4 xq = *(const float4*)&xs[c][ty * 4];
      float4 c0v = *(const float4*)&ct[c][tx * 8];
      float4 c1v = *(const float4*)&ct[c][tx * 8 + 4];
      float xm[4] = {xq.x, xq.y, xq.z, xq.w};
      float cq[8] = {c0v.x, c0v.y, c0v.z, c0v.w, c1v.x, c1v.y, c1v.z, c1v.w};
#pragma unroll
      for (int m = 0; m < 4; ++m)
#pragma unroll
        for (int j = 0; j < 8; ++j) acc[m][j] = fmaf(xm[m], cq[j], acc[m][j]);
    }
#pragma unroll
    for (int j = 0; j < 8; ++j) {
      int k = kt + tx * 8 + j;
      float cn = cnt[tx * 8 + j];
#pragma unroll
      for (int m = 0; m < 4; ++m) {
        float D = fmaf(-2.f, acc[m][j], cn);
        if (D < best[m]) {
          secd[m] = best[m]; si[m] = bi[m]; best[m] = D; bi[m] = k;
        } else if (D < secd[m]) {
          secd[m] = D; si[m] = k;
        }
      }
    }
    __syncthreads();  // protect ct before next tile's staging
  }
  // octet merge: xor 1,2,4 over tx bits (lane = (ty&3)*16+tx)
#pragma unroll
  for (int step = 1; step <= 4; step <<= 1) {
#pragma unroll
    for (int m = 0; m < 4; ++m) {
      float ob = __shfl_xor(best[m], step, 64);
      int oi = __shfl_xor(bi[m], step, 64);
      float os = __shfl_xor(secd[m], step, 64);
      int oj = __shfl_xor(si[m], step, 64);
      bool oW = (ob < best[m]) || (ob == best[m] && oi < bi[m]);
      float nb = oW ? ob : best[m];
      int ni = oW ? oi : bi[m];
      float lb = oW ? best[m] : ob;  // loser of best-compare
      int li = oW ? bi[m] : oi;
      float ws = oW ? os : secd[m];  // winner's second
      int wi = oW ? oj : si[m];
      bool sW = (ws < lb) || (ws == lb && wi < li);
      best[m] = nb; bi[m] = ni;
      secd[m] = sW ? ws : lb; si[m] = sW ? wi : li;
    }
  }
  if ((tx & 7) == 0) {
    int g = tx >> 3;
#pragma unroll
    for (int m = 0; m < 4; ++m) {
      int token = n0 + ty * 4 + m;
      cidx[(size_t)(g * 2 + 0) * NN + token] = bi[m];
      cidx[(size_t)(g * 2 + 1) * NN + token] = si[m];
    }
  }
}

// ============ kernel 4: exact fp64 select among 4 candidates ============
// thread = (token, cand); direct-form fp64 distance; lex-min (d, k).
__global__ __launch_bounds__(256) void vq_select(
    const float* __restrict__ xf, const float* __restrict__ cb,
    const int* __restrict__ cidx, int* __restrict__ sel) {
  int t = threadIdx.x;
  int n = blockIdx.x * 64 + (t >> 2);
  int cand = t & 3;
  int b = n >> 14, s = n & (SS - 1);
  int kj = cidx[(size_t)cand * NN + n];
  const float* xp = xf + (size_t)b * CC * SS + s;
  const float* cp = cb + (size_t)kj * CC;
  double dj = 0.0;
#pragma unroll 8
  for (int c = 0; c < CC; ++c) {
    double df = (double)xp[(size_t)c * SS] - (double)cp[c];
    dj = fma(df, df, dj);
  }
#pragma unroll
  for (int step = 1; step <= 2; step <<= 1) {
    double od = __shfl_xor(dj, step, 64);
    int ok = __shfl_xor(kj, step, 64);
    if (od < dj || (od == dj && ok < kj)) { dj = od; kj = ok; }
  }
  if (cand == 0) sel[n] = kj;
}

// ====== kernel 5: gather q, z-write, losses, conv_out (4x4 tile) ======
__global__ __launch_bounds__(256, 3) void vq_finish(
    const float* __restrict__ cb, const float* __restrict__ w_out,
    const float* __restrict__ b_out, const int* __restrict__ sel,
    float* __restrict__ dout, float* __restrict__ loss_acc) {
  __shared__ float qs[CC][BM];
  __shared__ float xs[CC][BM];
  __shared__ float wt[CC][CC];
  __shared__ int ids[BM];
  int t = threadIdx.x;
  int n0 = blockIdx.x * BM;
  int b = n0 >> 14, s0 = n0 & (SS - 1);
  float* zreg = dout + (size_t)NN * CC;
  if (t < BM) ids[t] = sel[n0 + t];
  {  // stage wt transposed
    int o = t >> 2, c0 = (t & 3) * 16;
    const float4* wr = (const float4*)(w_out + o * CC + c0);
#pragma unroll
    for (int i = 0; i < 4; ++i) {
      float4 v = wr[i];
      int ci = c0 + 4 * i;
      wt[ci + 0][o] = v.x; wt[ci + 1][o] = v.y;
      wt[ci + 2][o] = v.z; wt[ci + 3][o] = v.w;
    }
  }
#pragma unroll
  for (int i = 0; i < 4; ++i) {  // stage xs (= xf) from z region
    int e4 = t + 256 * i;
    int ci = e4 >> 4, tok4 = (e4 & 15) * 4;
    *(float4*)&xs[ci][tok4] = *(const float4*)(zreg + (size_t)b * CC * SS +
                                               (size_t)ci * SS + s0 + tok4);
  }
  __syncthreads();  // ids ready
  {  // stage qs[ch][tok] = codebook[ids[tok]]
    int tok = t >> 2, c0 = (t & 3) * 16;
    const float4* qr = (const float4*)(cb + (size_t)ids[tok] * CC + c0);
#pragma unroll
    for (int i = 0; i < 4; ++i) {
      float4 v = qr[i];
      int ch = c0 + 4 * i;
      qs[ch + 0][tok] = v.x; qs[ch + 1][tok] = v.y;
      qs[ch + 2][tok] = v.z; qs[ch + 3][tok] = v.w;
    }
  }
  __syncthreads();
  // losses + z := q (coalesced float4 rows)
  float lsum = 0.f;
#pragma unroll
  for (int i = 0; i < 4; ++i) {
    int e4 = t + 256 * i;
    int ci = e4 >> 4, tok4 = (e4 & 15) * 4;
    float4 qv = *(const float4*)&qs[ci][tok4];
    float4 xv = *(const float4*)&xs[ci][tok4];
    float dx = qv.x - xv.x, dy = qv.y - xv.y;
    float dz = qv.z - xv.z, dw = qv.w - xv.w;
    lsum = fmaf(dx, dx, lsum); lsum = fmaf(dy, dy, lsum);
    lsum = fmaf(dz, dz, lsum); lsum = fmaf(dw, dw, lsum);
    *(float4*)(zreg + (size_t)b * CC * SS + (size_t)ci * SS + s0 + tok4) = qv;
  }
  // conv_out: 4 tok x 4 oc per thread
  int tx = t & 15, ty = t >> 4;
  float acc[4][4];
#pragma unroll
  for (int j = 0; j < 4; ++j) {
    float bj = b_out[tx * 4 + j];
#pragma unroll
    for (int m = 0; m < 4; ++m) acc[m][j] = bj;
  }
#pragma unroll 8
  for (int ci = 0; ci < CC; ++ci) {
    float4 xq = *(const float4*)&qs[ci][ty * 4];
    float4 wq = *(const float4*)&wt[ci][tx * 4];
    float xm[4] = {xq.x, xq.y, xq.z, xq.w};
    float wm[4] = {wq.x, wq.y, wq.z, wq.w};
#pragma unroll
    for (int m = 0; m < 4; ++m)
#pragma unroll
      for (int j = 0; j < 4; ++j) acc[m][j] = fmaf(xm[m], wm[j], acc[m][j]);
  }
#pragma unroll
  for (int j = 0; j < 4; ++j) {
    float4 ov = make_float4(acc[0][j], acc[1][j], acc[2][j], acc[3][j]);
    *(float4*)(dout + (size_t)b * CC * SS + (size_t)(tx * 4 + j) * SS + s0 +
               ty * 4) = ov;
  }
  // loss reduce: wave shuffle + one atomic per block
#pragma unroll
  for (int off = 32; off > 0; off >>= 1) lsum += __shfl_down(lsum, off, 64);
  __shared__ float wsum[4];
  if ((t & 63) == 0) wsum[t >> 6] = lsum;
  __syncthreads();
  if (t == 0) atomicAdd(loss_acc, wsum[0] + wsum[1] + wsum[2] + wsum[3]);
}

// ============ kernel 6: finalize scalar losses ============
__global__ void vq_finalize(const float* __restrict__ loss_acc,
                            float* __restrict__ dout) {
  float l = loss_acc[0] * (1.0f / (float)((size_t)NN * CC));
  dout[(size_t)2 * NN * CC + 0] = l;  // codebook_loss
  dout[(size_t)2 * NN * CC + 1] = l;  // commitment_loss
}

extern "C" void kernel_launch(void* const* d_in, const int* in_sizes, int n_in,
                              void* d_out, int out_size, void* d_ws,
                              size_t ws_size, hipStream_t stream) {
  const float* x = (const float*)d_in[0];
  const float* cb = (const float*)d_in[1];
  const float* w_in = (const float*)d_in[2];
  const float* b_in = (const float*)d_in[3];
  const float* w_out = (const float*)d_in[4];
  const float* b_out = (const float*)d_in[5];
  float* out = (float*)d_out;
  float* zreg = out + (size_t)NN * CC;  // z region doubles as xf scratch

  // ws: [0,4) loss; [1024,9216) cnorm; [16K,272K) sel; [512K,1.5M) cidx
  float* loss_acc = (float*)d_ws;
  float* cnorm = (float*)((char*)d_ws + 1024);
  int* sel = (int*)((char*)d_ws + 16384);
  int* cidx = (int*)((char*)d_ws + 524288);

  hipMemsetAsync(d_ws, 0, 4, stream);

  vq_conv_in<<<NN / BM, 256, 0, stream>>>(x, w_in, b_in, zreg);
  vq_cnorm<<<KK / 256, 256, 0, stream>>>(cb, cnorm);
  vq_argmin<<<NN / BM, 256, 0, stream>>>(zreg, cb, cnorm, cidx);
  vq_select<<<NN / 64, 256, 0, stream>>>(zreg, cb, cidx, sel);
  vq_finish<<<NN / BM, 256, 0, stream>>>(cb, w_out, b_out, sel, out, loss_acc);
  vq_finalize<<<1, 1, 0, stream>>>(loss_acc, out);
}